// Round 17
// baseline (98.963 us; speedup 1.0000x reference)
//
#include <hip/hip_runtime.h>

#define EPS 1e-6f

typedef unsigned short u16;
typedef u16   u16x8  __attribute__((ext_vector_type(8)));
typedef float f32x4  __attribute__((ext_vector_type(4)));
typedef _Float16 f16x8 __attribute__((ext_vector_type(8)));

enum { BR_LIN = 0, BR_R6, BR_R5, BR_MIN, BR_R3, BR_XY, BR_R1, BR_R0 };

// ---------------- helpers ----------------
__device__ __forceinline__ u16 f2h(float f) { return __builtin_bit_cast(u16, (_Float16)f); }

__device__ __forceinline__ f32x4 mfma16(f16x8 a, f16x8 b, f32x4 c) {
  return __builtin_amdgcn_mfma_f32_16x16x32_f16(a, b, c, 0, 0, 0);
}

// 8 f32 -> f16x8 (RTE, bit-identical to prior rounds' LDS path)
__device__ __forceinline__ f16x8 cvt8(f32x4 lo, f32x4 hi) {
  f16x8 r;
  r[0] = (_Float16)lo[0]; r[1] = (_Float16)lo[1];
  r[2] = (_Float16)lo[2]; r[3] = (_Float16)lo[3];
  r[4] = (_Float16)hi[0]; r[5] = (_Float16)hi[1];
  r[6] = (_Float16)hi[2]; r[7] = (_Float16)hi[3];
  return r;
}

// hardware transcendentals: v_exp_f32 = 2^x, v_log_f32 = log2(x); 1 instr each.
__device__ __forceinline__ float fexp2(float x) {
  float r; asm("v_exp_f32 %0, %1" : "=v"(r) : "v"(x)); return r;
}
__device__ __forceinline__ float flog2(float x) {
  float r; asm("v_log_f32 %0, %1" : "=v"(r) : "v"(x)); return r;
}

__device__ __forceinline__ float r_poly_f(float a) {
  float d  = 0.5f - a;
  float d2 = d * d;
  float num = 0.25f + 1.65811f * d + 2.15388f * d2 + 8.2844f * d2 * d + 6.16764f * d2 * d2;
  float den = a * (1.0f - a);
  if (fabsf(den) < EPS) den = EPS;
  return num / den;
}

// ---- chain step: leaf-side precompute (carry-independent) + carry-dependent tail ----
// params: p0=[fx,w0,w1,s_lin] p1=[s_mn,s_xy,s_pm,s_pow] p2=[rs,rinv,cp,sx]
__device__ __forceinline__ void leaf_pre(float leaf, f32x4 p0, f32x4 p2,
                                         float& Y, float& w1Y, float& w1ey, float& cply) {
  float fx = p0[0], w1 = p0[2], rs = p2[0], cp = p2[2], sx = p2[3];
  float yy = fminf(fmaxf(leaf, EPS), 1.0f - EPS);
  Y = fmaf(sx, yy, fx);
  float ly = flog2(Y);
  w1Y  = w1 * Y;
  w1ey = w1 * fexp2(rs * ly);
  cply = cp * ly;
}

__device__ __forceinline__ float step_carry(float carry, float Y, float w1Y, float w1ey, float cply,
                                            f32x4 p0, f32x4 p1, f32x4 p2) {
  float fx = p0[0], w0 = p0[1], s_lin = p0[3];
  float s_mn = p1[0], s_xy = p1[1], s_pm = p1[2], s_pow = p1[3];
  float rs = p2[0], rinv = p2[1], cp = p2[2], sx = p2[3];

  float xx = fminf(fmaxf(carry, EPS), 1.0f - EPS);
  float X  = fmaf(sx, xx, fx);
  float lx = flog2(X);
  float pw = fexp2(fmaf(cp, lx, cply));
  float ex = fexp2(rs * lx);
  float s  = fmaf(w0, ex, w1ey);
  float pm = fexp2(rinv * flog2(s));

  float r = s_lin * fmaf(w0, X, w1Y);
  r = fmaf(s_mn, fminf(X, Y), r);
  r = fmaf(s_xy, X * Y, r);
  r = fmaf(s_pm, pm, r);
  r = fmaf(s_pow, pw, r);
  return fmaf(sx, r, fx);
}

// ---------------- kernel 1: Sinkhorn (register-resident) + fused param precompute ----------------
__global__ __launch_bounds__(1024, 4) void sinkhorn_kernel(
    const float* __restrict__ logits, u16* __restrict__ PTf,
    const float* __restrict__ W, const float* __restrict__ Bv,
    float* __restrict__ prm12) {
  const int t  = threadIdx.x;

  // ---- fused param precompute ----
  if (t < 255) {
    int i = t;
    float w0r = W[2 * i], w1r = W[2 * i + 1];
    float m  = fmaxf(w0r, w1r);
    float e0 = expf(w0r - m), e1 = expf(w1r - m);
    float inv = 1.0f / (e0 + e1);
    float w0 = e0 * inv, w1 = e1 * inv;

    float b   = Bv[i];
    float sig = 1.0f / (1.0f + expf(-b));
    float a_fb = sig * 3.0f - 1.0f;

    float a = a_fb;
    if (__builtin_isnan(a)) a = -1.0f;
    a = fminf(fmaxf(a, -1.0f + EPS), 2.0f - EPS);
    int flip = (a < 0.5f - EPS) ? 1 : 0;
    float aa = a;
    if (flip) aa = fminf(fmaxf(1.0f - a, -1.0f + EPS), 2.0f - EPS);

    int br; float c0 = 0.f, c1 = 0.f, c2 = 0.f, c3 = 0.f;
    if (fabsf(aa - 2.0f) < EPS) br = BR_R0;
    else if (aa > 1.25f && aa < 2.0f) {
      br = BR_R1;
      c0 = sqrtf(fmaxf(3.0f / fmaxf(2.0f - aa, EPS) - 1.0f, EPS));
    } else if (fabsf(aa - 1.25f) < EPS) br = BR_XY;
    else if (aa > 1.0f && aa < 1.25f) { br = BR_R3; c0 = 1.25f - aa; c1 = aa - 1.0f; }
    else if (fabsf(aa - 1.0f) < EPS) br = BR_MIN;
    else if (aa >= 0.75f && aa < 1.0f) {
      br = BR_R5;
      float ac = fminf(fmaxf(aa, 0.75f), 1.0f - EPS);
      float ra = r_poly_f(ac);
      if (fabsf(ra) < EPS) ra = EPS;
      c0 = ra; c1 = 1.0f / ra;
    } else if (aa > 0.5f && aa < 0.75f) {
      br = BR_R6;
      c0 = 3.0f - 4.0f * aa; c1 = 4.0f * aa - 2.0f;
      float R = r_poly_f(0.75f);
      if (fabsf(R) < EPS) R = EPS;
      c2 = R; c3 = 1.0f / R;
    } else br = BR_LIN;

    float s_lin = 0.f, s_mn = 0.f, s_xy = 0.f, s_pm = 0.f, s_pow = 0.f;
    float rs = 1.0f, rinv = 1.0f, cp = 0.0f;
    if (br == BR_R1)       { s_pow = 1.0f; cp = c0; }
    else if (br == BR_XY)  { s_xy = 1.0f; }
    else if (br == BR_R3)  { s_mn = 4.0f * c0; s_xy = 4.0f * c1; }
    else if (br == BR_MIN) { s_mn = 1.0f; }
    else if (br == BR_R5)  { s_pm = 1.0f; rs = c0; rinv = c1; }
    else if (br == BR_R6)  { s_lin = c0; s_pm = c1; rs = c2; rinv = c3; }
    else if (br == BR_LIN) { s_lin = 1.0f; }
    // BR_R0: all weights zero

    float* o12 = prm12 + i * 12;
    o12[0] = (float)flip; o12[1] = w0;  o12[2] = w1;   o12[3] = s_lin;
    o12[4] = s_mn;        o12[5] = s_xy; o12[6] = s_pm; o12[7] = s_pow;
    o12[8] = rs;          o12[9] = rinv; o12[10] = cp;  o12[11] = 1.0f - 2.0f * (float)flip;
  }

  // ---- Sinkhorn (register-resident, round-12 known-good) ----
  __shared__ float alpha[256], beta[256];
  __shared__ float psum[256][33];

  const int R  = t >> 5;
  const int C  = t & 31;
  const int r0 = R << 3;

  float e[8][8];
  #pragma unroll
  for (int dr = 0; dr < 8; ++dr) {
    const float* row = logits + (r0 + dr) * 256 + C;
    #pragma unroll
    for (int m = 0; m < 8; ++m) e[dr][m] = __expf(row[m << 5]);
  }

  if (t < 256) beta[t] = 1.0f;
  __syncthreads();

  for (int it = 0; it < 10; ++it) {
    {
      float bv[8], acc[8];
      #pragma unroll
      for (int m = 0; m < 8; ++m) bv[m] = beta[C + (m << 5)];
      #pragma unroll
      for (int dr = 0; dr < 8; ++dr) {
        float s = 0.f;
        #pragma unroll
        for (int m = 0; m < 8; ++m) s += e[dr][m] * bv[m];
        acc[dr] = s;
      }
      #pragma unroll
      for (int dr = 0; dr < 8; ++dr) psum[r0 + dr][C] = acc[dr];
    }
    __syncthreads();
    if (t < 256) {
      float s = 0.f;
      #pragma unroll
      for (int j = 0; j < 32; ++j) s += psum[t][j];
      alpha[t] = 1.0f / s;
    }
    __syncthreads();
    {
      float av[8], acc[8];
      #pragma unroll
      for (int dr = 0; dr < 8; ++dr) av[dr] = alpha[r0 + dr];
      #pragma unroll
      for (int m = 0; m < 8; ++m) {
        float s = 0.f;
        #pragma unroll
        for (int dr = 0; dr < 8; ++dr) s += e[dr][m] * av[dr];
        acc[m] = s;
      }
      #pragma unroll
      for (int m = 0; m < 8; ++m) psum[C + (m << 5)][R] = acc[m];
    }
    __syncthreads();
    if (t < 256) {
      float s = 0.f;
      #pragma unroll
      for (int j = 0; j < 32; ++j) s += psum[t][j];
      beta[t] = 1.0f / s;
    }
    __syncthreads();
  }

  float av[8], bv[8];
  #pragma unroll
  for (int dr = 0; dr < 8; ++dr) av[dr] = alpha[r0 + dr];
  #pragma unroll
  for (int m = 0; m < 8; ++m) bv[m] = beta[C + (m << 5)];

  #pragma unroll
  for (int m = 0; m < 8; ++m) {
    int l = C + (m << 5);
    u16x8 vh;
    #pragma unroll
    for (int dr = 0; dr < 8; ++dr) vh[dr] = f2h(av[dr] * e[dr][m] * bv[m]);
    *(u16x8*)(PTf + l * 256 + r0) = vh;
  }
}

// ---------------- kernel 2: barrier-free direct-load GEMM + fused chain ----------------
// 256 thr = 4 waves (2M x 2N), b-tile 64, K-step 32, NO LDS staging, NO k-loop
// barriers. Per lane per kc: A = 8 u16x8 direct from PTf (L2-hot, fp16 already);
// B = 2x(2 f32x4) from x, ping-pong prefetched 1 tile ahead, RTE cvt in-register.
// Fragment values identical to the staged path -> numerics bit-identical.
// LDS only for epilogue: cbuf[64][68]@0 (17408 B), qlds@17408 (12240 B).
#define CSTR 68

// one K-step: convert current B, prefetch next B, stream A + MFMA
#define GEMM_BODY(KC, BCUR, BNXT)                                              \
  {                                                                            \
    f16x8 bh0 = cvt8(BCUR[0], BCUR[1]);                                        \
    f16x8 bh1 = cvt8(BCUR[2], BCUR[3]);                                        \
    if ((KC) < 7) {                                                            \
      int kn = ((KC) + 1) << 5;                                                \
      BNXT[0] = *(const f32x4*)(xb0 + kn);                                     \
      BNXT[1] = *(const f32x4*)(xb0 + kn + 4);                                 \
      BNXT[2] = *(const f32x4*)(xb1 + kn);                                     \
      BNXT[3] = *(const f32x4*)(xb1 + kn + 4);                                 \
    }                                                                          \
    int ka = ((KC) << 5) + k0;                                                 \
    _Pragma("unroll")                                                          \
    for (int mf = 0; mf < 8; ++mf) {                                           \
      u16x8 avr = *(const u16x8*)(pa + mf * 4096 + ka);                        \
      f16x8 ah  = __builtin_bit_cast(f16x8, avr);                              \
      acc[mf][0] = mfma16(ah, bh0, acc[mf][0]);                                \
      acc[mf][1] = mfma16(ah, bh1, acc[mf][1]);                                \
    }                                                                          \
  }

__global__ __launch_bounds__(256, 4) void gemm_chain_kernel(
    const float* __restrict__ x, const u16* __restrict__ PTf,
    const float* __restrict__ prm12, float* __restrict__ out) {
  __shared__ __align__(16) char smem[30720];
  float* cbuf = (float*)smem;                // [64][CSTR] = 17408 B
  float* qlds = (float*)(smem + 17408);      // 3060 floats (node params)

  const int t    = threadIdx.x;
  const int w    = t >> 6;
  const int lane = t & 63;
  const int bl   = lane & 15;
  const int kh   = lane >> 4;
  const int wm   = w >> 1;                   // 0..1 (l half)
  const int wn   = w & 1;                    // 0..1 (b half)
  const int b0   = blockIdx.x * 64;

  // chain params into LDS
  for (int j = t; j < 3060; j += 256) qlds[j] = prm12[j];

  f32x4 acc[8][2];
  #pragma unroll
  for (int m = 0; m < 8; ++m) {
    acc[m][0] = f32x4{0.f, 0.f, 0.f, 0.f};
    acc[m][1] = f32x4{0.f, 0.f, 0.f, 0.f};
  }

  // per-lane fragment base pointers
  const float* xb0 = x + (size_t)(b0 + (wn << 5) + bl) * 256 + (kh << 3);        // nf=0 row
  const float* xb1 = xb0 + 16 * 256;                                             // nf=1 row
  const u16*   pa  = PTf + ((wm << 7) + bl) * 256;                               // mf=0 row
  const int    k0  = kh << 3;

  // B ping-pong register sets
  f32x4 bxA[4], bxB[4];
  bxA[0] = *(const f32x4*)(xb0);
  bxA[1] = *(const f32x4*)(xb0 + 4);
  bxA[2] = *(const f32x4*)(xb1);
  bxA[3] = *(const f32x4*)(xb1 + 4);

  GEMM_BODY(0, bxA, bxB)
  GEMM_BODY(1, bxB, bxA)
  GEMM_BODY(2, bxA, bxB)
  GEMM_BODY(3, bxB, bxA)
  GEMM_BODY(4, bxA, bxB)
  GEMM_BODY(5, bxB, bxA)
  GEMM_BODY(6, bxA, bxB)
  GEMM_BODY(7, bxB, bxA)

  // ---- fused chain epilogue (identical to round 16) ----
  float carry = 0.0f;

  #pragma unroll
  for (int c = 0; c < 4; ++c) {
    __syncthreads();
    if (wm == (c >> 1)) {
      #pragma unroll
      for (int d = 0; d < 4; ++d) {
        int mf = ((c & 1) << 2) + d;
        #pragma unroll
        for (int nf = 0; nf < 2; ++nf) {
          int bc = (wn << 5) + (nf << 4) + bl;
          #pragma unroll
          for (int r = 0; r < 4; ++r) {
            int lr = (d << 4) + (kh << 2) + r;
            cbuf[lr * CSTR + bc] = acc[mf][nf][r];
          }
        }
      }
    }
    __syncthreads();
    if (t < 64) {
      int lc0 = 0;
      if (c == 0) {
        float v0 = cbuf[0 * CSTR + t];
        float v1 = cbuf[1 * CSTR + t];
        float v2 = cbuf[2 * CSTR + t];
        float v3 = cbuf[3 * CSTR + t];
        carry = v0;
        float vv[3] = {v1, v2, v3};
        #pragma unroll
        for (int u = 0; u < 3; ++u) {
          const float* qn = qlds + u * 12;
          f32x4 P0 = *(const f32x4*)(qn), P1 = *(const f32x4*)(qn + 4), P2 = *(const f32x4*)(qn + 8);
          float Y, w1Y, w1ey, cply;
          leaf_pre(vv[u], P0, P2, Y, w1Y, w1ey, cply);
          carry = step_carry(carry, Y, w1Y, w1ey, cply, P0, P1, P2);
        }
        lc0 = 4;
      }
      for (int lc = lc0; lc < 64; lc += 4) {
        float v[4];
        #pragma unroll
        for (int u = 0; u < 4; ++u) v[u] = cbuf[(lc + u) * CSTR + t];
        f32x4 P0[4], P1[4], P2[4];
        #pragma unroll
        for (int u = 0; u < 4; ++u) {
          const float* qn = qlds + ((c << 6) + lc + u - 1) * 12;
          P0[u] = *(const f32x4*)(qn);
          P1[u] = *(const f32x4*)(qn + 4);
          P2[u] = *(const f32x4*)(qn + 8);
        }
        float Y[4], w1Y[4], w1ey[4], cply[4];
        #pragma unroll
        for (int u = 0; u < 4; ++u)
          leaf_pre(v[u], P0[u], P2[u], Y[u], w1Y[u], w1ey[u], cply[u]);
        #pragma unroll
        for (int u = 0; u < 4; ++u)
          carry = step_carry(carry, Y[u], w1Y[u], w1ey[u], cply[u], P0[u], P1[u], P2[u]);
      }
    }
  }
  if (t < 64) out[b0 + t] = carry;
}

// ---------------- launch ----------------
extern "C" void kernel_launch(void* const* d_in, const int* in_sizes, int n_in,
                              void* d_out, int out_size, void* d_ws, size_t ws_size,
                              hipStream_t stream) {
  const float* x       = (const float*)d_in[0];   // (65536, 256)
  const float* logits  = (const float*)d_in[1];   // (256, 256)
  const float* weights = (const float*)d_in[2];   // (255, 2)
  const float* biases  = (const float*)d_in[3];   // (255,)
  float* out = (float*)d_out;                     // (65536, 1)

  char* ws = (char*)d_ws;
  int Btot = in_sizes[0] / 256;                   // 65536

  u16*   PTf   = (u16*)ws;                        // 131072 B (fp16 P^T)
  float* prm12 = (float*)(ws + 131072);           // 12240 B

  sinkhorn_kernel<<<1, 1024, 0, stream>>>(logits, PTf, weights, biases, prm12);
  gemm_chain_kernel<<<Btot / 64, 256, 0, stream>>>(x, PTf, prm12, out);
}

// Round 18
// 76.724 us; speedup vs baseline: 1.2899x; 1.2899x over previous
//
#include <hip/hip_runtime.h>

#define EPS 1e-6f

typedef unsigned short u16;
typedef u16   u16x4  __attribute__((ext_vector_type(4)));
typedef u16   u16x8  __attribute__((ext_vector_type(8)));
typedef float f32x4  __attribute__((ext_vector_type(4)));
typedef _Float16 f16x8 __attribute__((ext_vector_type(8)));

enum { BR_LIN = 0, BR_R6, BR_R5, BR_MIN, BR_R3, BR_XY, BR_R1, BR_R0 };

// ---------------- helpers ----------------
__device__ __forceinline__ u16 f2h(float f) { return __builtin_bit_cast(u16, (_Float16)f); }

__device__ __forceinline__ f16x8 lds_f16x8(const u16* p) {
  u16x8 r = *(const u16x8*)p;
  return __builtin_bit_cast(f16x8, r);
}

__device__ __forceinline__ f32x4 mfma16(f16x8 a, f16x8 b, f32x4 c) {
  return __builtin_amdgcn_mfma_f32_16x16x32_f16(a, b, c, 0, 0, 0);
}

// hardware transcendentals: v_exp_f32 = 2^x, v_log_f32 = log2(x); 1 instr each.
__device__ __forceinline__ float fexp2(float x) {
  float r; asm("v_exp_f32 %0, %1" : "=v"(r) : "v"(x)); return r;
}
__device__ __forceinline__ float flog2(float x) {
  float r; asm("v_log_f32 %0, %1" : "=v"(r) : "v"(x)); return r;
}

__device__ __forceinline__ float r_poly_f(float a) {
  float d  = 0.5f - a;
  float d2 = d * d;
  float num = 0.25f + 1.65811f * d + 2.15388f * d2 + 8.2844f * d2 * d + 6.16764f * d2 * d2;
  float den = a * (1.0f - a);
  if (fabsf(den) < EPS) den = EPS;
  return num / den;
}

// ---- chain step: leaf-side precompute (carry-independent) + carry-dependent tail ----
// params: p0=[fx,w0,w1,s_lin] p1=[s_mn,s_xy,s_pm,s_pow] p2=[rs,rinv,cp,sx]
__device__ __forceinline__ void leaf_pre(float leaf, f32x4 p0, f32x4 p2,
                                         float& Y, float& w1Y, float& w1ey, float& cply) {
  float fx = p0[0], w1 = p0[2], rs = p2[0], cp = p2[2], sx = p2[3];
  float yy = fminf(fmaxf(leaf, EPS), 1.0f - EPS);
  Y = fmaf(sx, yy, fx);
  float ly = flog2(Y);
  w1Y  = w1 * Y;
  w1ey = w1 * fexp2(rs * ly);
  cply = cp * ly;
}

__device__ __forceinline__ float step_carry(float carry, float Y, float w1Y, float w1ey, float cply,
                                            f32x4 p0, f32x4 p1, f32x4 p2) {
  float fx = p0[0], w0 = p0[1], s_lin = p0[3];
  float s_mn = p1[0], s_xy = p1[1], s_pm = p1[2], s_pow = p1[3];
  float rs = p2[0], rinv = p2[1], cp = p2[2], sx = p2[3];

  float xx = fminf(fmaxf(carry, EPS), 1.0f - EPS);
  float X  = fmaf(sx, xx, fx);
  float lx = flog2(X);
  float pw = fexp2(fmaf(cp, lx, cply));
  float ex = fexp2(rs * lx);
  float s  = fmaf(w0, ex, w1ey);
  float pm = fexp2(rinv * flog2(s));

  float r = s_lin * fmaf(w0, X, w1Y);
  r = fmaf(s_mn, fminf(X, Y), r);
  r = fmaf(s_xy, X * Y, r);
  r = fmaf(s_pm, pm, r);
  r = fmaf(s_pow, pw, r);
  return fmaf(sx, r, fx);
}

// ---------------- kernel 1: Sinkhorn (register-resident) + fused param precompute ----------------
__global__ __launch_bounds__(1024, 4) void sinkhorn_kernel(
    const float* __restrict__ logits, u16* __restrict__ PTf,
    const float* __restrict__ W, const float* __restrict__ Bv,
    float* __restrict__ prm12) {
  const int t  = threadIdx.x;

  // ---- fused param precompute (runs before the register-heavy section) ----
  if (t < 255) {
    int i = t;
    float w0r = W[2 * i], w1r = W[2 * i + 1];
    float m  = fmaxf(w0r, w1r);
    float e0 = expf(w0r - m), e1 = expf(w1r - m);
    float inv = 1.0f / (e0 + e1);
    float w0 = e0 * inv, w1 = e1 * inv;

    float b   = Bv[i];
    float sig = 1.0f / (1.0f + expf(-b));
    float a_fb = sig * 3.0f - 1.0f;

    float a = a_fb;
    if (__builtin_isnan(a)) a = -1.0f;
    a = fminf(fmaxf(a, -1.0f + EPS), 2.0f - EPS);
    int flip = (a < 0.5f - EPS) ? 1 : 0;
    float aa = a;
    if (flip) aa = fminf(fmaxf(1.0f - a, -1.0f + EPS), 2.0f - EPS);

    int br; float c0 = 0.f, c1 = 0.f, c2 = 0.f, c3 = 0.f;
    if (fabsf(aa - 2.0f) < EPS) br = BR_R0;
    else if (aa > 1.25f && aa < 2.0f) {
      br = BR_R1;
      c0 = sqrtf(fmaxf(3.0f / fmaxf(2.0f - aa, EPS) - 1.0f, EPS));
    } else if (fabsf(aa - 1.25f) < EPS) br = BR_XY;
    else if (aa > 1.0f && aa < 1.25f) { br = BR_R3; c0 = 1.25f - aa; c1 = aa - 1.0f; }
    else if (fabsf(aa - 1.0f) < EPS) br = BR_MIN;
    else if (aa >= 0.75f && aa < 1.0f) {
      br = BR_R5;
      float ac = fminf(fmaxf(aa, 0.75f), 1.0f - EPS);
      float ra = r_poly_f(ac);
      if (fabsf(ra) < EPS) ra = EPS;
      c0 = ra; c1 = 1.0f / ra;
    } else if (aa > 0.5f && aa < 0.75f) {
      br = BR_R6;
      c0 = 3.0f - 4.0f * aa; c1 = 4.0f * aa - 2.0f;
      float R = r_poly_f(0.75f);
      if (fabsf(R) < EPS) R = EPS;
      c2 = R; c3 = 1.0f / R;
    } else br = BR_LIN;

    float s_lin = 0.f, s_mn = 0.f, s_xy = 0.f, s_pm = 0.f, s_pow = 0.f;
    float rs = 1.0f, rinv = 1.0f, cp = 0.0f;
    if (br == BR_R1)       { s_pow = 1.0f; cp = c0; }
    else if (br == BR_XY)  { s_xy = 1.0f; }
    else if (br == BR_R3)  { s_mn = 4.0f * c0; s_xy = 4.0f * c1; }
    else if (br == BR_MIN) { s_mn = 1.0f; }
    else if (br == BR_R5)  { s_pm = 1.0f; rs = c0; rinv = c1; }
    else if (br == BR_R6)  { s_lin = c0; s_pm = c1; rs = c2; rinv = c3; }
    else if (br == BR_LIN) { s_lin = 1.0f; }
    // BR_R0: all weights zero

    float* o12 = prm12 + i * 12;
    o12[0] = (float)flip; o12[1] = w0;  o12[2] = w1;   o12[3] = s_lin;
    o12[4] = s_mn;        o12[5] = s_xy; o12[6] = s_pm; o12[7] = s_pow;
    o12[8] = rs;          o12[9] = rinv; o12[10] = cp;  o12[11] = 1.0f - 2.0f * (float)flip;
  }

  // ---- Sinkhorn (register-resident, round-12 known-good) ----
  __shared__ float alpha[256], beta[256];
  __shared__ float psum[256][33];

  const int R  = t >> 5;
  const int C  = t & 31;
  const int r0 = R << 3;

  float e[8][8];
  #pragma unroll
  for (int dr = 0; dr < 8; ++dr) {
    const float* row = logits + (r0 + dr) * 256 + C;
    #pragma unroll
    for (int m = 0; m < 8; ++m) e[dr][m] = __expf(row[m << 5]);
  }

  if (t < 256) beta[t] = 1.0f;
  __syncthreads();

  for (int it = 0; it < 10; ++it) {
    {
      float bv[8], acc[8];
      #pragma unroll
      for (int m = 0; m < 8; ++m) bv[m] = beta[C + (m << 5)];
      #pragma unroll
      for (int dr = 0; dr < 8; ++dr) {
        float s = 0.f;
        #pragma unroll
        for (int m = 0; m < 8; ++m) s += e[dr][m] * bv[m];
        acc[dr] = s;
      }
      #pragma unroll
      for (int dr = 0; dr < 8; ++dr) psum[r0 + dr][C] = acc[dr];
    }
    __syncthreads();
    if (t < 256) {
      float s = 0.f;
      #pragma unroll
      for (int j = 0; j < 32; ++j) s += psum[t][j];
      alpha[t] = 1.0f / s;
    }
    __syncthreads();
    {
      float av[8], acc[8];
      #pragma unroll
      for (int dr = 0; dr < 8; ++dr) av[dr] = alpha[r0 + dr];
      #pragma unroll
      for (int m = 0; m < 8; ++m) {
        float s = 0.f;
        #pragma unroll
        for (int dr = 0; dr < 8; ++dr) s += e[dr][m] * av[dr];
        acc[m] = s;
      }
      #pragma unroll
      for (int m = 0; m < 8; ++m) psum[C + (m << 5)][R] = acc[m];
    }
    __syncthreads();
    if (t < 256) {
      float s = 0.f;
      #pragma unroll
      for (int j = 0; j < 32; ++j) s += psum[t][j];
      beta[t] = 1.0f / s;
    }
    __syncthreads();
  }

  float av[8], bv[8];
  #pragma unroll
  for (int dr = 0; dr < 8; ++dr) av[dr] = alpha[r0 + dr];
  #pragma unroll
  for (int m = 0; m < 8; ++m) bv[m] = beta[C + (m << 5)];

  #pragma unroll
  for (int m = 0; m < 8; ++m) {
    int l = C + (m << 5);
    u16x8 vh;
    #pragma unroll
    for (int dr = 0; dr < 8; ++dr) vh[dr] = f2h(av[dr] * e[dr][m] * bv[m]);
    *(u16x8*)(PTf + l * 256 + r0) = vh;
  }
}

// ---------------- kernel 2: fused fp16 GEMM + branchless HW-trans chain ----------------
// 256 thr = 4 waves (2M x 2N), b-tile 64, K-step 32, swizzled LDS (0 staging
// conflicts). Grid 1024 -> 4 blocks/CU: independent blocks stagger phases.
// Change vs round 16: next-tile prefetch issues BEFORE the W barrier (adds
// barrier-wait to the HBM-latency cover window; no hazard - regs consumed above).
// Map: xs[64][32]@0 (4K), pt[256][32]@4096 (16K), qlds@20480 (12240);
// epilogue alias cbuf[64][68]@0 (17408).
#define CSTR 68

__global__ __launch_bounds__(256, 4) void gemm_chain_kernel(
    const float* __restrict__ x, const u16* __restrict__ PTf,
    const float* __restrict__ prm12, float* __restrict__ out) {
  __shared__ __align__(16) char smem[32768];
  u16* xs = (u16*)smem;                      // [64][32] fp16 (swizzled groups)
  u16* pt = (u16*)(smem + 4096);             // [256][32] fp16 (swizzled groups)
  float* qlds = (float*)(smem + 20480);      // 3060 floats (node params)
  float* cbuf = (float*)smem;                // [64][CSTR] epilogue alias

  const int t    = threadIdx.x;
  const int w    = t >> 6;
  const int lane = t & 63;
  const int bl   = lane & 15;
  const int kh   = lane >> 4;
  const int wm   = w >> 1;                   // 0..1 (l half)
  const int wn   = w & 1;                    // 0..1 (b half)
  const int b0   = blockIdx.x * 64;

  const int xrow = t >> 2;                   // 0..63
  const int xsl  = t & 3;                    // base f32x4 slot

  // chain params into LDS (region disjoint from staging)
  for (int j = t; j < 3060; j += 256) qlds[j] = prm12[j];

  f32x4 acc[8][2];
  #pragma unroll
  for (int m = 0; m < 8; ++m) {
    acc[m][0] = f32x4{0.f, 0.f, 0.f, 0.f};
    acc[m][1] = f32x4{0.f, 0.f, 0.f, 0.f};
  }

  f32x4 xr[2];
  u16x8 pr[4];

  // prologue: prefetch tile 0 (PT with pre-swizzled source)
  #pragma unroll
  for (int j = 0; j < 2; ++j)
    xr[j] = *(const f32x4*)(x + (b0 + xrow) * 256 + ((xsl + 4 * j) << 2));
  #pragma unroll
  for (int j = 0; j < 4; ++j) {
    int c = t + 256 * j, r = c >> 2, s = c & 3, g = s ^ ((r >> 1) & 3);
    pr[j] = *(const u16x8*)(PTf + r * 256 + (g << 3));
  }

  for (int kc = 0; kc < 8; ++kc) {
    // ---- W phase: write prefetched tile to LDS ----
    #pragma unroll
    for (int j = 0; j < 2; ++j) {
      int slot = xsl + 4 * j;
      u16x4 hv;
      #pragma unroll
      for (int e = 0; e < 4; ++e) hv[e] = f2h(xr[j][e]);
      int g = slot >> 1, sub = slot & 1;
      *(u16x4*)(xs + xrow * 32 + ((g ^ ((xrow >> 1) & 3)) << 3) + (sub << 2)) = hv;
    }
    #pragma unroll
    for (int j = 0; j < 4; ++j)
      *(u16x8*)(pt + ((t + 256 * j) << 3)) = pr[j];   // linear (content pre-swizzled)

    // ---- issue next-tile prefetch BEFORE the barrier (regs consumed above) ----
    if (kc < 7) {
      int k1 = (kc + 1) << 5;
      #pragma unroll
      for (int j = 0; j < 2; ++j)
        xr[j] = *(const f32x4*)(x + (b0 + xrow) * 256 + k1 + ((xsl + 4 * j) << 2));
      #pragma unroll
      for (int j = 0; j < 4; ++j) {
        int c = t + 256 * j, r = c >> 2, s = c & 3, g = s ^ ((r >> 1) & 3);
        pr[j] = *(const u16x8*)(PTf + r * 256 + k1 + (g << 3));
      }
    }
    __syncthreads();

    // ---- C phase ----
    f16x8 bh[2];
    #pragma unroll
    for (int nf = 0; nf < 2; ++nf) {
      int brow = (wn << 5) + (nf << 4) + bl;
      bh[nf] = lds_f16x8(xs + brow * 32 + ((kh ^ ((brow >> 1) & 3)) << 3));
    }
    #pragma unroll
    for (int mf = 0; mf < 8; ++mf) {
      int arow = (wm << 7) + (mf << 4) + bl;
      f16x8 ah = lds_f16x8(pt + arow * 32 + ((kh ^ ((arow >> 1) & 3)) << 3));
      #pragma unroll
      for (int nf = 0; nf < 2; ++nf)
        acc[mf][nf] = mfma16(ah, bh[nf], acc[mf][nf]);
    }
    __syncthreads();
  }

  // ---- fused chain epilogue ----
  float carry = 0.0f;

  #pragma unroll
  for (int c = 0; c < 4; ++c) {
    __syncthreads();
    // waves with wm == c>>1 dump l-chunk [64c, 64c+64) into cbuf[l'][b]
    if (wm == (c >> 1)) {
      #pragma unroll
      for (int d = 0; d < 4; ++d) {
        int mf = ((c & 1) << 2) + d;
        #pragma unroll
        for (int nf = 0; nf < 2; ++nf) {
          int bc = (wn << 5) + (nf << 4) + bl;
          #pragma unroll
          for (int r = 0; r < 4; ++r) {
            int lr = (d << 4) + (kh << 2) + r;
            cbuf[lr * CSTR + bc] = acc[mf][nf][r];
          }
        }
      }
    }
    __syncthreads();
    if (t < 64) {
      int lc0 = 0;
      if (c == 0) {
        float v0 = cbuf[0 * CSTR + t];
        float v1 = cbuf[1 * CSTR + t];
        float v2 = cbuf[2 * CSTR + t];
        float v3 = cbuf[3 * CSTR + t];
        carry = v0;
        float vv[3] = {v1, v2, v3};
        #pragma unroll
        for (int u = 0; u < 3; ++u) {
          const float* qn = qlds + u * 12;
          f32x4 P0 = *(const f32x4*)(qn), P1 = *(const f32x4*)(qn + 4), P2 = *(const f32x4*)(qn + 8);
          float Y, w1Y, w1ey, cply;
          leaf_pre(vv[u], P0, P2, Y, w1Y, w1ey, cply);
          carry = step_carry(carry, Y, w1Y, w1ey, cply, P0, P1, P2);
        }
        lc0 = 4;
      }
      for (int lc = lc0; lc < 64; lc += 4) {
        float v[4];
        #pragma unroll
        for (int u = 0; u < 4; ++u) v[u] = cbuf[(lc + u) * CSTR + t];
        f32x4 P0[4], P1[4], P2[4];
        #pragma unroll
        for (int u = 0; u < 4; ++u) {
          const float* qn = qlds + ((c << 6) + lc + u - 1) * 12;
          P0[u] = *(const f32x4*)(qn);
          P1[u] = *(const f32x4*)(qn + 4);
          P2[u] = *(const f32x4*)(qn + 8);
        }
        float Y[4], w1Y[4], w1ey[4], cply[4];
        #pragma unroll
        for (int u = 0; u < 4; ++u)
          leaf_pre(v[u], P0[u], P2[u], Y[u], w1Y[u], w1ey[u], cply[u]);
        #pragma unroll
        for (int u = 0; u < 4; ++u)
          carry = step_carry(carry, Y[u], w1Y[u], w1ey[u], cply[u], P0[u], P1[u], P2[u]);
      }
    }
  }
  if (t < 64) out[b0 + t] = carry;
}

// ---------------- launch ----------------
extern "C" void kernel_launch(void* const* d_in, const int* in_sizes, int n_in,
                              void* d_out, int out_size, void* d_ws, size_t ws_size,
                              hipStream_t stream) {
  const float* x       = (const float*)d_in[0];   // (65536, 256)
  const float* logits  = (const float*)d_in[1];   // (256, 256)
  const float* weights = (const float*)d_in[2];   // (255, 2)
  const float* biases  = (const float*)d_in[3];   // (255,)
  float* out = (float*)d_out;                     // (65536, 1)

  char* ws = (char*)d_ws;
  int Btot = in_sizes[0] / 256;                   // 65536

  u16*   PTf   = (u16*)ws;                        // 131072 B (fp16 P^T)
  float* prm12 = (float*)(ws + 131072);           // 12240 B

  sinkhorn_kernel<<<1, 1024, 0, stream>>>(logits, PTf, weights, biases, prm12);
  gemm_chain_kernel<<<Btot / 64, 256, 0, stream>>>(x, PTf, prm12, out);
}

// Round 19
// 70.022 us; speedup vs baseline: 1.4133x; 1.0957x over previous
//
#include <hip/hip_runtime.h>

#define EPS 1e-6f

typedef unsigned short u16;
typedef u16   u16x4  __attribute__((ext_vector_type(4)));
typedef u16   u16x8  __attribute__((ext_vector_type(8)));
typedef float f32x4  __attribute__((ext_vector_type(4)));
typedef _Float16 f16x8 __attribute__((ext_vector_type(8)));

enum { BR_LIN = 0, BR_R6, BR_R5, BR_MIN, BR_R3, BR_XY, BR_R1, BR_R0 };

// ---------------- helpers ----------------
__device__ __forceinline__ u16 f2h(float f) { return __builtin_bit_cast(u16, (_Float16)f); }

__device__ __forceinline__ f16x8 lds_f16x8(const u16* p) {
  u16x8 r = *(const u16x8*)p;
  return __builtin_bit_cast(f16x8, r);
}

__device__ __forceinline__ f32x4 mfma16(f16x8 a, f16x8 b, f32x4 c) {
  return __builtin_amdgcn_mfma_f32_16x16x32_f16(a, b, c, 0, 0, 0);
}

// hardware transcendentals: v_exp_f32 = 2^x, v_log_f32 = log2(x); 1 instr each.
__device__ __forceinline__ float fexp2(float x) {
  float r; asm("v_exp_f32 %0, %1" : "=v"(r) : "v"(x)); return r;
}
__device__ __forceinline__ float flog2(float x) {
  float r; asm("v_log_f32 %0, %1" : "=v"(r) : "v"(x)); return r;
}

__device__ __forceinline__ float r_poly_f(float a) {
  float d  = 0.5f - a;
  float d2 = d * d;
  float num = 0.25f + 1.65811f * d + 2.15388f * d2 + 8.2844f * d2 * d + 6.16764f * d2 * d2;
  float den = a * (1.0f - a);
  if (fabsf(den) < EPS) den = EPS;
  return num / den;
}

// ---- chain step: leaf-side precompute (carry-independent) + carry-dependent tail ----
// params: p0=[fx,w0,w1,s_lin] p1=[s_mn,s_xy,s_pm,s_pow] p2=[rs,rinv,cp,sx]
__device__ __forceinline__ void leaf_pre(float leaf, f32x4 p0, f32x4 p2,
                                         float& Y, float& w1Y, float& w1ey, float& cply) {
  float fx = p0[0], w1 = p0[2], rs = p2[0], cp = p2[2], sx = p2[3];
  float yy = fminf(fmaxf(leaf, EPS), 1.0f - EPS);
  Y = fmaf(sx, yy, fx);
  float ly = flog2(Y);
  w1Y  = w1 * Y;
  w1ey = w1 * fexp2(rs * ly);
  cply = cp * ly;
}

__device__ __forceinline__ float step_carry(float carry, float Y, float w1Y, float w1ey, float cply,
                                            f32x4 p0, f32x4 p1, f32x4 p2) {
  float fx = p0[0], w0 = p0[1], s_lin = p0[3];
  float s_mn = p1[0], s_xy = p1[1], s_pm = p1[2], s_pow = p1[3];
  float rs = p2[0], rinv = p2[1], cp = p2[2], sx = p2[3];

  float xx = fminf(fmaxf(carry, EPS), 1.0f - EPS);
  float X  = fmaf(sx, xx, fx);
  float lx = flog2(X);
  float pw = fexp2(fmaf(cp, lx, cply));
  float ex = fexp2(rs * lx);
  float s  = fmaf(w0, ex, w1ey);
  float pm = fexp2(rinv * flog2(s));

  float r = s_lin * fmaf(w0, X, w1Y);
  r = fmaf(s_mn, fminf(X, Y), r);
  r = fmaf(s_xy, X * Y, r);
  r = fmaf(s_pm, pm, r);
  r = fmaf(s_pow, pw, r);
  return fmaf(sx, r, fx);
}

// ---------------- kernel 1: Sinkhorn (register-resident) + fused param precompute ----------------
__global__ __launch_bounds__(1024, 4) void sinkhorn_kernel(
    const float* __restrict__ logits, u16* __restrict__ PTf,
    const float* __restrict__ W, const float* __restrict__ Bv,
    float* __restrict__ prm12) {
  const int t  = threadIdx.x;

  // ---- fused param precompute (runs before the register-heavy section) ----
  if (t < 255) {
    int i = t;
    float w0r = W[2 * i], w1r = W[2 * i + 1];
    float m  = fmaxf(w0r, w1r);
    float e0 = expf(w0r - m), e1 = expf(w1r - m);
    float inv = 1.0f / (e0 + e1);
    float w0 = e0 * inv, w1 = e1 * inv;

    float b   = Bv[i];
    float sig = 1.0f / (1.0f + expf(-b));
    float a_fb = sig * 3.0f - 1.0f;

    float a = a_fb;
    if (__builtin_isnan(a)) a = -1.0f;
    a = fminf(fmaxf(a, -1.0f + EPS), 2.0f - EPS);
    int flip = (a < 0.5f - EPS) ? 1 : 0;
    float aa = a;
    if (flip) aa = fminf(fmaxf(1.0f - a, -1.0f + EPS), 2.0f - EPS);

    int br; float c0 = 0.f, c1 = 0.f, c2 = 0.f, c3 = 0.f;
    if (fabsf(aa - 2.0f) < EPS) br = BR_R0;
    else if (aa > 1.25f && aa < 2.0f) {
      br = BR_R1;
      c0 = sqrtf(fmaxf(3.0f / fmaxf(2.0f - aa, EPS) - 1.0f, EPS));
    } else if (fabsf(aa - 1.25f) < EPS) br = BR_XY;
    else if (aa > 1.0f && aa < 1.25f) { br = BR_R3; c0 = 1.25f - aa; c1 = aa - 1.0f; }
    else if (fabsf(aa - 1.0f) < EPS) br = BR_MIN;
    else if (aa >= 0.75f && aa < 1.0f) {
      br = BR_R5;
      float ac = fminf(fmaxf(aa, 0.75f), 1.0f - EPS);
      float ra = r_poly_f(ac);
      if (fabsf(ra) < EPS) ra = EPS;
      c0 = ra; c1 = 1.0f / ra;
    } else if (aa > 0.5f && aa < 0.75f) {
      br = BR_R6;
      c0 = 3.0f - 4.0f * aa; c1 = 4.0f * aa - 2.0f;
      float R = r_poly_f(0.75f);
      if (fabsf(R) < EPS) R = EPS;
      c2 = R; c3 = 1.0f / R;
    } else br = BR_LIN;

    float s_lin = 0.f, s_mn = 0.f, s_xy = 0.f, s_pm = 0.f, s_pow = 0.f;
    float rs = 1.0f, rinv = 1.0f, cp = 0.0f;
    if (br == BR_R1)       { s_pow = 1.0f; cp = c0; }
    else if (br == BR_XY)  { s_xy = 1.0f; }
    else if (br == BR_R3)  { s_mn = 4.0f * c0; s_xy = 4.0f * c1; }
    else if (br == BR_MIN) { s_mn = 1.0f; }
    else if (br == BR_R5)  { s_pm = 1.0f; rs = c0; rinv = c1; }
    else if (br == BR_R6)  { s_lin = c0; s_pm = c1; rs = c2; rinv = c3; }
    else if (br == BR_LIN) { s_lin = 1.0f; }
    // BR_R0: all weights zero

    float* o12 = prm12 + i * 12;
    o12[0] = (float)flip; o12[1] = w0;  o12[2] = w1;   o12[3] = s_lin;
    o12[4] = s_mn;        o12[5] = s_xy; o12[6] = s_pm; o12[7] = s_pow;
    o12[8] = rs;          o12[9] = rinv; o12[10] = cp;  o12[11] = 1.0f - 2.0f * (float)flip;
  }

  // ---- Sinkhorn (register-resident, round-12 known-good) ----
  __shared__ float alpha[256], beta[256];
  __shared__ float psum[256][33];

  const int R  = t >> 5;
  const int C  = t & 31;
  const int r0 = R << 3;

  float e[8][8];
  #pragma unroll
  for (int dr = 0; dr < 8; ++dr) {
    const float* row = logits + (r0 + dr) * 256 + C;
    #pragma unroll
    for (int m = 0; m < 8; ++m) e[dr][m] = __expf(row[m << 5]);
  }

  if (t < 256) beta[t] = 1.0f;
  __syncthreads();

  for (int it = 0; it < 10; ++it) {
    {
      float bv[8], acc[8];
      #pragma unroll
      for (int m = 0; m < 8; ++m) bv[m] = beta[C + (m << 5)];
      #pragma unroll
      for (int dr = 0; dr < 8; ++dr) {
        float s = 0.f;
        #pragma unroll
        for (int m = 0; m < 8; ++m) s += e[dr][m] * bv[m];
        acc[dr] = s;
      }
      #pragma unroll
      for (int dr = 0; dr < 8; ++dr) psum[r0 + dr][C] = acc[dr];
    }
    __syncthreads();
    if (t < 256) {
      float s = 0.f;
      #pragma unroll
      for (int j = 0; j < 32; ++j) s += psum[t][j];
      alpha[t] = 1.0f / s;
    }
    __syncthreads();
    {
      float av[8], acc[8];
      #pragma unroll
      for (int dr = 0; dr < 8; ++dr) av[dr] = alpha[r0 + dr];
      #pragma unroll
      for (int m = 0; m < 8; ++m) {
        float s = 0.f;
        #pragma unroll
        for (int dr = 0; dr < 8; ++dr) s += e[dr][m] * av[dr];
        acc[m] = s;
      }
      #pragma unroll
      for (int m = 0; m < 8; ++m) psum[C + (m << 5)][R] = acc[m];
    }
    __syncthreads();
    if (t < 256) {
      float s = 0.f;
      #pragma unroll
      for (int j = 0; j < 32; ++j) s += psum[t][j];
      beta[t] = 1.0f / s;
    }
    __syncthreads();
  }

  float av[8], bv[8];
  #pragma unroll
  for (int dr = 0; dr < 8; ++dr) av[dr] = alpha[r0 + dr];
  #pragma unroll
  for (int m = 0; m < 8; ++m) bv[m] = beta[C + (m << 5)];

  #pragma unroll
  for (int m = 0; m < 8; ++m) {
    int l = C + (m << 5);
    u16x8 vh;
    #pragma unroll
    for (int dr = 0; dr < 8; ++dr) vh[dr] = f2h(av[dr] * e[dr][m] * bv[m]);
    *(u16x8*)(PTf + l * 256 + r0) = vh;
  }
}

// ---------------- kernel 2: fused fp16 GEMM + branchless HW-trans chain ----------------
// Round-16 structure (validated best): 256 thr = 4 waves (2M x 2N), b-tile 64,
// K-step 32, swizzled LDS, 4 blocks/CU. ONE change: k-loop barriers are raw
// s_barrier with lgkmcnt(0)-only waits (no vmcnt drain) so the C-phase-issued
// prefetch loads stay in flight across the post-C barrier (T4 principle).
// Map: xs[64][32]@0 (4K), pt[256][32]@4096 (16K), qlds@20480 (12240);
// epilogue alias cbuf[64][68]@0 (17408).
#define CSTR 68

__global__ __launch_bounds__(256, 4) void gemm_chain_kernel(
    const float* __restrict__ x, const u16* __restrict__ PTf,
    const float* __restrict__ prm12, float* __restrict__ out) {
  __shared__ __align__(16) char smem[32768];
  u16* xs = (u16*)smem;                      // [64][32] fp16 (swizzled groups)
  u16* pt = (u16*)(smem + 4096);             // [256][32] fp16 (swizzled groups)
  float* qlds = (float*)(smem + 20480);      // 3060 floats (node params)
  float* cbuf = (float*)smem;                // [64][CSTR] epilogue alias

  const int t    = threadIdx.x;
  const int w    = t >> 6;
  const int lane = t & 63;
  const int bl   = lane & 15;
  const int kh   = lane >> 4;
  const int wm   = w >> 1;                   // 0..1 (l half)
  const int wn   = w & 1;                    // 0..1 (b half)
  const int b0   = blockIdx.x * 64;

  const int xrow = t >> 2;                   // 0..63
  const int xsl  = t & 3;                    // base f32x4 slot

  // chain params into LDS (region disjoint from staging)
  for (int j = t; j < 3060; j += 256) qlds[j] = prm12[j];

  f32x4 acc[8][2];
  #pragma unroll
  for (int m = 0; m < 8; ++m) {
    acc[m][0] = f32x4{0.f, 0.f, 0.f, 0.f};
    acc[m][1] = f32x4{0.f, 0.f, 0.f, 0.f};
  }

  f32x4 xr[2];
  u16x8 pr[4];

  // prologue: prefetch tile 0 (PT with pre-swizzled source)
  #pragma unroll
  for (int j = 0; j < 2; ++j)
    xr[j] = *(const f32x4*)(x + (b0 + xrow) * 256 + ((xsl + 4 * j) << 2));
  #pragma unroll
  for (int j = 0; j < 4; ++j) {
    int c = t + 256 * j, r = c >> 2, s = c & 3, g = s ^ ((r >> 1) & 3);
    pr[j] = *(const u16x8*)(PTf + r * 256 + (g << 3));
  }

  for (int kc = 0; kc < 8; ++kc) {
    // ---- W phase: write prefetched tile to LDS ----
    #pragma unroll
    for (int j = 0; j < 2; ++j) {
      int slot = xsl + 4 * j;
      u16x4 hv;
      #pragma unroll
      for (int e = 0; e < 4; ++e) hv[e] = f2h(xr[j][e]);
      int g = slot >> 1, sub = slot & 1;
      *(u16x4*)(xs + xrow * 32 + ((g ^ ((xrow >> 1) & 3)) << 3) + (sub << 2)) = hv;
    }
    #pragma unroll
    for (int j = 0; j < 4; ++j)
      *(u16x8*)(pt + ((t + 256 * j) << 3)) = pr[j];   // linear (content pre-swizzled)

    // post-W barrier: LDS writes must be visible; do NOT drain vmcnt
    asm volatile("s_waitcnt lgkmcnt(0)" ::: "memory");
    __builtin_amdgcn_s_barrier();

    // ---- prefetch next tile (issued here; flies across the post-C barrier) ----
    if (kc < 7) {
      int k1 = (kc + 1) << 5;
      #pragma unroll
      for (int j = 0; j < 2; ++j)
        xr[j] = *(const f32x4*)(x + (b0 + xrow) * 256 + k1 + ((xsl + 4 * j) << 2));
      #pragma unroll
      for (int j = 0; j < 4; ++j) {
        int c = t + 256 * j, r = c >> 2, s = c & 3, g = s ^ ((r >> 1) & 3);
        pr[j] = *(const u16x8*)(PTf + r * 256 + k1 + (g << 3));
      }
    }

    // ---- C phase ----
    f16x8 bh[2];
    #pragma unroll
    for (int nf = 0; nf < 2; ++nf) {
      int brow = (wn << 5) + (nf << 4) + bl;
      bh[nf] = lds_f16x8(xs + brow * 32 + ((kh ^ ((brow >> 1) & 3)) << 3));
    }
    #pragma unroll
    for (int mf = 0; mf < 8; ++mf) {
      int arow = (wm << 7) + (mf << 4) + bl;
      f16x8 ah = lds_f16x8(pt + arow * 32 + ((kh ^ ((arow >> 1) & 3)) << 3));
      #pragma unroll
      for (int nf = 0; nf < 2; ++nf)
        acc[mf][nf] = mfma16(ah, bh[nf], acc[mf][nf]);
    }

    // post-C barrier: all frag reads already consumed by MFMAs; no vmcnt drain
    asm volatile("s_waitcnt lgkmcnt(0)" ::: "memory");
    __builtin_amdgcn_s_barrier();
  }

  // ---- fused chain epilogue (full __syncthreads; nothing in flight) ----
  float carry = 0.0f;

  #pragma unroll
  for (int c = 0; c < 4; ++c) {
    __syncthreads();
    // waves with wm == c>>1 dump l-chunk [64c, 64c+64) into cbuf[l'][b]
    if (wm == (c >> 1)) {
      #pragma unroll
      for (int d = 0; d < 4; ++d) {
        int mf = ((c & 1) << 2) + d;
        #pragma unroll
        for (int nf = 0; nf < 2; ++nf) {
          int bc = (wn << 5) + (nf << 4) + bl;
          #pragma unroll
          for (int r = 0; r < 4; ++r) {
            int lr = (d << 4) + (kh << 2) + r;
            cbuf[lr * CSTR + bc] = acc[mf][nf][r];
          }
        }
      }
    }
    __syncthreads();
    if (t < 64) {
      int lc0 = 0;
      if (c == 0) {
        float v0 = cbuf[0 * CSTR + t];
        float v1 = cbuf[1 * CSTR + t];
        float v2 = cbuf[2 * CSTR + t];
        float v3 = cbuf[3 * CSTR + t];
        carry = v0;
        float vv[3] = {v1, v2, v3};
        #pragma unroll
        for (int u = 0; u < 3; ++u) {
          const float* qn = qlds + u * 12;
          f32x4 P0 = *(const f32x4*)(qn), P1 = *(const f32x4*)(qn + 4), P2 = *(const f32x4*)(qn + 8);
          float Y, w1Y, w1ey, cply;
          leaf_pre(vv[u], P0, P2, Y, w1Y, w1ey, cply);
          carry = step_carry(carry, Y, w1Y, w1ey, cply, P0, P1, P2);
        }
        lc0 = 4;
      }
      for (int lc = lc0; lc < 64; lc += 4) {
        float v[4];
        #pragma unroll
        for (int u = 0; u < 4; ++u) v[u] = cbuf[(lc + u) * CSTR + t];
        f32x4 P0[4], P1[4], P2[4];
        #pragma unroll
        for (int u = 0; u < 4; ++u) {
          const float* qn = qlds + ((c << 6) + lc + u - 1) * 12;
          P0[u] = *(const f32x4*)(qn);
          P1[u] = *(const f32x4*)(qn + 4);
          P2[u] = *(const f32x4*)(qn + 8);
        }
        float Y[4], w1Y[4], w1ey[4], cply[4];
        #pragma unroll
        for (int u = 0; u < 4; ++u)
          leaf_pre(v[u], P0[u], P2[u], Y[u], w1Y[u], w1ey[u], cply[u]);
        #pragma unroll
        for (int u = 0; u < 4; ++u)
          carry = step_carry(carry, Y[u], w1Y[u], w1ey[u], cply[u], P0[u], P1[u], P2[u]);
      }
    }
  }
  if (t < 64) out[b0 + t] = carry;
}

// ---------------- launch ----------------
extern "C" void kernel_launch(void* const* d_in, const int* in_sizes, int n_in,
                              void* d_out, int out_size, void* d_ws, size_t ws_size,
                              hipStream_t stream) {
  const float* x       = (const float*)d_in[0];   // (65536, 256)
  const float* logits  = (const float*)d_in[1];   // (256, 256)
  const float* weights = (const float*)d_in[2];   // (255, 2)
  const float* biases  = (const float*)d_in[3];   // (255,)
  float* out = (float*)d_out;                     // (65536, 1)

  char* ws = (char*)d_ws;
  int Btot = in_sizes[0] / 256;                   // 65536

  u16*   PTf   = (u16*)ws;                        // 131072 B (fp16 P^T)
  float* prm12 = (float*)(ws + 131072);           // 12240 B

  sinkhorn_kernel<<<1, 1024, 0, stream>>>(logits, PTf, weights, biases, prm12);
  gemm_chain_kernel<<<Btot / 64, 256, 0, stream>>>(x, PTf, prm12, out);
}